// Round 11
// baseline (143.117 us; speedup 1.0000x reference)
//
#include <hip/hip_runtime.h>
#include <hip/hip_fp16.h>

// CRF NLL on MI355X — round 20: BIDIRECTIONAL combine (alpha + beta chains).
//
// r19 post-mortem: 4-chain ILP neutral (TLP already covers MFMA shadow).
// All real wins came from shortening the serial combine tail. r20 halves it:
// answer = a0^T·F_0···F_15 · (F_16···F_31·e). Waves 4-7 compute their chunk
// products TRANSPOSED: F^T = diag(s31)·W^T·diag(s30)···diag(s0)·W^T — the
// identical pack->MFMA step with (1) A-fragments gathered transposed
// (trans[k*32+n]), (2) D-init = W^T (exp(trans[n][row])) instead of I,
// (3) ascending scale consumption + final row-scale fixup. Stored column-
// per-lane as before => column n of F^T = row n of F, so the beta chain
// v <- F_c·v uses the SAME replicated-vector combine code. Wave0 runs the
// alpha chain over chunks 0..15 while wave1 concurrently runs beta over
// 31..16; barrier; wave0 finishes with log(u·v). Serial tail 32 -> 16 iters
// and the z-epilogue folds into beta's init. Everything else = r18/r19.
//
// ws layout (dwords): [0,16384) per-wave score/msum/napp slots (b*32+w*4);
//   [16384, 16896) per-block results.
// Scale 2^-6.5 per applied matrix (exact: added back as napp*6.5*ln2).

typedef __attribute__((ext_vector_type(8)))  _Float16 half8;
typedef __attribute__((ext_vector_type(2)))  _Float16 half2v;
typedef __attribute__((ext_vector_type(16))) float    f32x16;
typedef __attribute__((ext_vector_type(4)))  unsigned uint4v;

#define S_N 1024
#define T_N 32
#define B_N 512
#define L_CH 32
#define C_CH 32
#define SCALE_MUL 0.011048543456039806f   // 2^-6.5 folded into ee
#define SCALE_LOG 4.505456673639645f      // 6.5*ln2 per applied matrix

#define WS_RES_OFF 16384                  // dword offset of per-block results

__device__ __forceinline__ unsigned pkrtz(float lo, float hi) {
    return __builtin_bit_cast(unsigned, __builtin_amdgcn_cvt_pkrtz(lo, hi));
}
__device__ __forceinline__ unsigned pmul(unsigned a, unsigned b) {
    const __half2 r = __builtin_bit_cast(__half2, a) * __builtin_bit_cast(__half2, b);
    return __builtin_bit_cast(unsigned, r);
}
__device__ __forceinline__ half8 mkh8(const unsigned* a) {
    uint4v u = {a[0], a[1], a[2], a[3]};
    return __builtin_bit_cast(half8, u);
}
__device__ __forceinline__ float hlo(unsigned u) {
    return (float)__builtin_bit_cast(half2v, u).x;
}
__device__ __forceinline__ float hhi(unsigned u) {
    return (float)__builtin_bit_cast(half2v, u).y;
}
// PI: involution swapping rows 4-7<->8-11 and 20-23<->24-27
__device__ __forceinline__ int PIx(int x) { return (x & ~12) | ((x & 4) << 1) | ((x & 8) >> 1); }

__device__ __forceinline__ f32x16 packmm(const f32x16& D, uint4 su, uint4 sv,
                                         half8 A1v, half8 A2v) {
    unsigned S[8];
    S[0] = pmul(pkrtz(D[0],  D[1]),  su.x);
    S[1] = pmul(pkrtz(D[2],  D[3]),  su.y);
    S[2] = pmul(pkrtz(D[4],  D[5]),  su.z);
    S[3] = pmul(pkrtz(D[6],  D[7]),  su.w);
    S[4] = pmul(pkrtz(D[8],  D[9]),  sv.x);
    S[5] = pmul(pkrtz(D[10], D[11]), sv.y);
    S[6] = pmul(pkrtz(D[12], D[13]), sv.z);
    S[7] = pmul(pkrtz(D[14], D[15]), sv.w);
    const f32x16 Z = {};
    f32x16 t = __builtin_amdgcn_mfma_f32_32x32x16_f16(A1v, mkh8(&S[0]), Z, 0, 0, 0);
    return   __builtin_amdgcn_mfma_f32_32x32x16_f16(A2v, mkh8(&S[4]), t, 0, 0, 0);
}
__device__ __forceinline__ void step1(f32x16& D, const unsigned* mq, int r, int h,
                                      half8 A1v, half8 A2v) {
    const uint4 su = *(const uint4*)(mq + r * 16 + h * 8);
    const uint4 sv = *(const uint4*)(mq + r * 16 + h * 8 + 4);
    D = packmm(D, su, sv, A1v, A2v);
}
// final row-scale fixup for transposed chains: D <- diag(s_r)·D
#define FIXUP(D, mq, r_) { \
    const uint4 su = *(const uint4*)((mq) + (r_) * 16 + h * 8); \
    const uint4 sv = *(const uint4*)((mq) + (r_) * 16 + h * 8 + 4); \
    D[0] *= hlo(su.x); D[1] *= hhi(su.x); D[2]  *= hlo(su.y); D[3]  *= hhi(su.y); \
    D[4] *= hlo(su.z); D[5] *= hhi(su.z); D[6]  *= hlo(su.w); D[7]  *= hhi(su.w); \
    D[8] *= hlo(sv.x); D[9] *= hhi(sv.x); D[10] *= hlo(sv.y); D[11] *= hhi(sv.y); \
    D[12] *= hlo(sv.z); D[13] *= hhi(sv.z); D[14] *= hlo(sv.w); D[15] *= hhi(sv.w); }

template<bool CLEAN>
__device__ __forceinline__ void chain4(
    const unsigned* m0, const unsigned* m1,
    const unsigned* m2, const unsigned* m3,
    f32x16& D0, f32x16& D1, f32x16& D2, f32x16& D3,
    unsigned mb0, unsigned mb1, unsigned mb2, unsigned mb3,
    int h, half8 A1v, half8 A2v) {
    if (CLEAN) {
        #pragma unroll 2
        for (int r = L_CH - 1; r >= 1; --r) {
            const uint4 su0 = *(const uint4*)(m0 + r * 16 + h * 8);
            const uint4 sv0 = *(const uint4*)(m0 + r * 16 + h * 8 + 4);
            const uint4 su1 = *(const uint4*)(m1 + r * 16 + h * 8);
            const uint4 sv1 = *(const uint4*)(m1 + r * 16 + h * 8 + 4);
            const uint4 su2 = *(const uint4*)(m2 + r * 16 + h * 8);
            const uint4 sv2 = *(const uint4*)(m2 + r * 16 + h * 8 + 4);
            const uint4 su3 = *(const uint4*)(m3 + r * 16 + h * 8);
            const uint4 sv3 = *(const uint4*)(m3 + r * 16 + h * 8 + 4);
            D0 = packmm(D0, su0, sv0, A1v, A2v);
            D1 = packmm(D1, su1, sv1, A1v, A2v);
            D2 = packmm(D2, su2, sv2, A1v, A2v);
            D3 = packmm(D3, su3, sv3, A1v, A2v);
        }
        if (mb0 & 1u) step1(D0, m0, 0, h, A1v, A2v);   // chunk 0 has bit0 cleared
        if (mb1 & 1u) step1(D1, m1, 0, h, A1v, A2v);
        if (mb2 & 1u) step1(D2, m2, 0, h, A1v, A2v);
        if (mb3 & 1u) step1(D3, m3, 0, h, A1v, A2v);
    } else {
        for (int r = L_CH - 1; r >= 0; --r) {
            if ((mb0 >> r) & 1u) step1(D0, m0, r, h, A1v, A2v);
            if ((mb1 >> r) & 1u) step1(D1, m1, r, h, A1v, A2v);
            if ((mb2 >> r) & 1u) step1(D2, m2, r, h, A1v, A2v);
            if ((mb3 >> r) & 1u) step1(D3, m3, r, h, A1v, A2v);
        }
    }
}

// transposed chunk chain (clean masks): D pre-initialized to W^T; consumes
// scale rows 0..30 ascending, then fixup row 31.  F^T accumulates in D.
__device__ __forceinline__ void tchain4_clean(
    const unsigned* m0, const unsigned* m1,
    const unsigned* m2, const unsigned* m3,
    f32x16& D0, f32x16& D1, f32x16& D2, f32x16& D3,
    int h, half8 A1v, half8 A2v) {
    #pragma unroll 2
    for (int q = 0; q < L_CH - 1; ++q) {
        const uint4 su0 = *(const uint4*)(m0 + q * 16 + h * 8);
        const uint4 sv0 = *(const uint4*)(m0 + q * 16 + h * 8 + 4);
        const uint4 su1 = *(const uint4*)(m1 + q * 16 + h * 8);
        const uint4 sv1 = *(const uint4*)(m1 + q * 16 + h * 8 + 4);
        const uint4 su2 = *(const uint4*)(m2 + q * 16 + h * 8);
        const uint4 sv2 = *(const uint4*)(m2 + q * 16 + h * 8 + 4);
        const uint4 su3 = *(const uint4*)(m3 + q * 16 + h * 8);
        const uint4 sv3 = *(const uint4*)(m3 + q * 16 + h * 8 + 4);
        D0 = packmm(D0, su0, sv0, A1v, A2v);
        D1 = packmm(D1, su1, sv1, A1v, A2v);
        D2 = packmm(D2, su2, sv2, A1v, A2v);
        D3 = packmm(D3, su3, sv3, A1v, A2v);
    }
    FIXUP(D0, m0, 31) FIXUP(D1, m1, 31) FIXUP(D2, m2, 31) FIXUP(D3, m3, 31)
}
// transposed masked fallback (rare; one chunk). D pre-initialized to W^T.
__device__ __forceinline__ void tchain1_masked(
    f32x16& D, const unsigned* mq, unsigned mb, int h, int n,
    half8 A1v, half8 A2v) {
    int prev = -1;
    for (int r = 0; r < 32; ++r) {
        if ((mb >> r) & 1u) {
            if (prev >= 0) step1(D, mq, prev, h, A1v, A2v);
            prev = r;
        }
    }
    if (prev >= 0) { FIXUP(D, mq, prev) }
    else {
        #pragma unroll
        for (int i = 0; i < 16; ++i) {
            const int row = (i & 3) + 8 * (i >> 2) + 4 * h;
            D[i] = (row == n) ? 1.0f : 0.0f;
        }
    }
}

__global__ __attribute__((amdgpu_flat_work_group_size(512, 512),
                          amdgpu_waves_per_eu(4, 4)))
void crf_fused(
    const float* __restrict__ em, const int* __restrict__ tags,
    const float* __restrict__ mask, const float* __restrict__ trans,
    const float* __restrict__ startT, const float* __restrict__ endT,
    float* __restrict__ wspart, float* __restrict__ out)
{
    __shared__ unsigned elds[C_CH][512];   // 64 KiB: scales, reused for fragments
    __shared__ float abuf[2][32];          // per-wave alpha/beta broadcast
    __shared__ float lb[2];                // Lacc_alpha, Lacc_beta

    const int wib  = threadIdx.x >> 6;     // 0..7
    const int lane = threadIdx.x & 63;
    const int n    = lane & 31;
    const int h    = lane >> 5;
    const int b    = blockIdx.x;
    const int c0   = wib * 4;              // this wave's first chunk
    const bool betaw = (wib >= 4);         // chunks 16-31: transposed products

    // ---- issue pair-0 emission loads immediately (16B/lane, linear) ----
    float4 P0[4], P1[4];
    {
        const float4* eq0 = (const float4*)(em + ((size_t)b * S_N + (c0 + 0) * L_CH) * T_N);
        const float4* eq1 = (const float4*)(em + ((size_t)b * S_N + (c0 + 1) * L_CH) * T_N);
        #pragma unroll
        for (int i = 0; i < 4; ++i) P0[i] = eq0[i * 64 + lane];
        #pragma unroll
        for (int i = 0; i < 4; ++i) P1[i] = eq1[i * 64 + lane];
    }

    // ---- mask ballots (4 chunks = 128 positions) + path-score partial ----
    unsigned mb_[4];
    {
        float vacc = 0.f, macc = 0.f;
        #pragma unroll
        for (int q2 = 0; q2 < 2; ++q2) {
            const int s  = c0 * L_CH + q2 * 64 + lane;
            const float mv = mask[b * S_N + s];
            const unsigned long long mb = __ballot(mv != 0.0f);
            mb_[2 * q2]     = (unsigned)mb;
            mb_[2 * q2 + 1] = (unsigned)(mb >> 32);
            const int tc = tags[b * S_N + s];
            int tp = __shfl_up(tc, 1, 64);
            float val;
            if (lane == 0) {
                if (s == 0) {
                    val = startT[tc] + em[(size_t)b * S_N * T_N + tc];
                } else {
                    tp = tags[b * S_N + s - 1];
                    val = mv * (em[((size_t)b * S_N + s) * T_N + tc] + trans[tp * 32 + tc]);
                }
            } else {
                val = mv * (em[((size_t)b * S_N + s) * T_N + tc] + trans[tp * 32 + tc]);
            }
            vacc += val; macc += mv;
        }
        if (c0 == 0) mb_[0] &= ~1u;        // t=0 has no transition matrix
        #pragma unroll
        for (int d = 32; d > 0; d >>= 1) {
            vacc += __shfl_xor(vacc, d, 64);
            macc += __shfl_xor(macc, d, 64);
        }
        if (lane == 0) {
            float* slot = wspart + (size_t)b * 32 + wib * 4;
            slot[0] = vacc;
            slot[1] = macc;
            slot[2] = (float)(__popc(mb_[0]) + __popc(mb_[1]) +
                              __popc(mb_[2]) + __popc(mb_[3]));
        }
    }

    // pack loaded f32 quads -> f16 scale pairs in D-reg-pair LDS order.
    #define PACKQ(P, qc) { \
        unsigned* mq = elds[qc]; \
        _Pragma("unroll") \
        for (int i = 0; i < 4; ++i) { \
            const int f = i * 64 + lane; \
            const int r_ = f >> 3; \
            const int m_ = ((f & 1) << 3) | (f & 6); \
            const unsigned pk0 = pkrtz(__expf(P[i].x) * SCALE_MUL, __expf(P[i].y) * SCALE_MUL); \
            const unsigned pk1 = pkrtz(__expf(P[i].z) * SCALE_MUL, __expf(P[i].w) * SCALE_MUL); \
            *(uint2*)(mq + r_ * 16 + m_) = make_uint2(pk0, pk1); \
        } }

    PACKQ(P0, c0)
    PACKQ(P1, c0 + 1)

    // ---- issue pair-1 loads; latency covered by A-frag setup + D-init ----
    {
        const float4* eq2 = (const float4*)(em + ((size_t)b * S_N + (c0 + 2) * L_CH) * T_N);
        const float4* eq3 = (const float4*)(em + ((size_t)b * S_N + (c0 + 3) * L_CH) * T_N);
        #pragma unroll
        for (int i = 0; i < 4; ++i) P0[i] = eq2[i * 64 + lane];
        #pragma unroll
        for (int i = 0; i < 4; ++i) P1[i] = eq3[i * 64 + lane];
    }

    // ---- A fragments: forward waves W = exp(trans[n][k]); beta waves W^T ----
    unsigned A1[4], A2[4];
    #pragma unroll
    for (int j = 0; j < 4; ++j) {
        const int k1 = PIx(8 * h + 2 * j);
        const int k2 = PIx(16 + 8 * h + 2 * j);
        if (!betaw) {
            A1[j] = pkrtz(__expf(trans[n * 32 + k1]), __expf(trans[n * 32 + k1 + 1]));
            A2[j] = pkrtz(__expf(trans[n * 32 + k2]), __expf(trans[n * 32 + k2 + 1]));
        } else {
            A1[j] = pkrtz(__expf(trans[k1 * 32 + n]), __expf(trans[(k1 + 1) * 32 + n]));
            A2[j] = pkrtz(__expf(trans[k2 * 32 + n]), __expf(trans[(k2 + 1) * 32 + n]));
        }
    }
    const half8 A1v = mkh8(A1), A2v = mkh8(A2);

    // ---- chain states: identity (forward) or W^T (beta) in C layout ----
    f32x16 D0, D1, D2, D3;
    #pragma unroll
    for (int i = 0; i < 16; ++i) {
        const int row = (i & 3) + 8 * (i >> 2) + 4 * h;
        const float v = betaw ? __expf(trans[n * 32 + row])
                              : ((row == n) ? 1.0f : 0.0f);
        D0[i] = v; D1[i] = v; D2[i] = v; D3[i] = v;
    }

    PACKQ(P0, c0 + 2)
    PACKQ(P1, c0 + 3)
    #undef PACKQ

    const bool allclean =
        ((mb_[0] | (c0 == 0 ? 1u : 0u)) == 0xFFFFFFFFu) &&
        (mb_[1] == 0xFFFFFFFFu) && (mb_[2] == 0xFFFFFFFFu) && (mb_[3] == 0xFFFFFFFFu);

    if (!betaw) {
        if (allclean)
            chain4<true >(elds[c0], elds[c0 + 1], elds[c0 + 2], elds[c0 + 3],
                          D0, D1, D2, D3, mb_[0], mb_[1], mb_[2], mb_[3], h, A1v, A2v);
        else
            chain4<false>(elds[c0], elds[c0 + 1], elds[c0 + 2], elds[c0 + 3],
                          D0, D1, D2, D3, mb_[0], mb_[1], mb_[2], mb_[3], h, A1v, A2v);
    } else {
        if (allclean)
            tchain4_clean(elds[c0], elds[c0 + 1], elds[c0 + 2], elds[c0 + 3],
                          D0, D1, D2, D3, h, A1v, A2v);
        else {
            tchain1_masked(D0, elds[c0],     mb_[0], h, n, A1v, A2v);
            tchain1_masked(D1, elds[c0 + 1], mb_[1], h, n, A1v, A2v);
            tchain1_masked(D2, elds[c0 + 2], mb_[2], h, n, A1v, A2v);
            tchain1_masked(D3, elds[c0 + 3], mb_[3], h, n, A1v, A2v);
        }
    }

    // fragment store: own LDS rows (scales dead), dense SoA, stride-16B
    #define STOREF(D, qc) { \
        unsigned* dst = elds[qc]; \
        ((uint4*)dst)[lane]      = make_uint4(pkrtz(D[0], D[1]),   pkrtz(D[2], D[3]), \
                                              pkrtz(D[4], D[5]),   pkrtz(D[6], D[7])); \
        ((uint4*)dst)[64 + lane] = make_uint4(pkrtz(D[8], D[9]),   pkrtz(D[10], D[11]), \
                                              pkrtz(D[12], D[13]), pkrtz(D[14], D[15])); \
    }
    STOREF(D0, c0) STOREF(D1, c0 + 1) STOREF(D2, c0 + 2) STOREF(D3, c0 + 3)
    #undef STOREF

    __syncthreads();                        // all fragments + ws slots visible

    // ---- bidirectional combine: wave0 alpha (0..15), wave1 beta (31..16) ----
    if (wib <= 1) {
        float* ab = abuf[wib];
        float Ar[32];
        float Lacc;
        if (wib == 0) {
            const float a0 = startT[n] + em[(size_t)b * S_N * T_N + n];
            ab[n] = a0;
            #pragma unroll
            for (int k = 0; k < 8; ++k) {
                const float4 t = *(const float4*)&ab[k * 4];
                Ar[4 * k] = t.x; Ar[4 * k + 1] = t.y; Ar[4 * k + 2] = t.z; Ar[4 * k + 3] = t.w;
            }
            float mx = Ar[0];
            #pragma unroll
            for (int r = 1; r < 32; ++r) mx = fmaxf(mx, Ar[r]);
            Lacc = mx;
            #pragma unroll
            for (int r = 0; r < 32; ++r) Ar[r] = __expf(Ar[r] - mx);
        } else {
            Lacc = 0.0f;
            #pragma unroll
            for (int k = 0; k < 8; ++k) {
                const float4 t = *(const float4*)&endT[k * 4];
                Ar[4 * k]     = __expf(t.x);
                Ar[4 * k + 1] = __expf(t.y);
                Ar[4 * k + 2] = __expf(t.z);
                Ar[4 * k + 3] = __expf(t.w);
            }
        }

        #define ACC8(f, B) { \
            p0 = fmaf(Ar[(B) + 0],  hlo((f).x), p0); \
            p1 = fmaf(Ar[(B) + 1],  hhi((f).x), p1); \
            p2 = fmaf(Ar[(B) + 2],  hlo((f).y), p2); \
            p3 = fmaf(Ar[(B) + 3],  hhi((f).y), p3); \
            p0 = fmaf(Ar[(B) + 8],  hlo((f).z), p0); \
            p1 = fmaf(Ar[(B) + 9],  hhi((f).z), p1); \
            p2 = fmaf(Ar[(B) + 10], hlo((f).w), p2); \
            p3 = fmaf(Ar[(B) + 11], hhi((f).w), p3); }

        for (int cc = 0; cc < 4; ++cc) {    // 16 serial iterations per wave
            #pragma unroll
            for (int k = 0; k < 4; ++k) {
                const int t = cc * 4 + k;
                const int c = (wib == 0) ? t : (31 - t);
                const unsigned* ch = elds[c];
                const uint4 f00 = *(const uint4*)(ch + n * 4);
                const uint4 f01 = *(const uint4*)(ch + (n + 32) * 4);
                const uint4 f10 = *(const uint4*)(ch + 256 + n * 4);
                const uint4 f11 = *(const uint4*)(ch + 256 + (n + 32) * 4);

                float p0 = 0.f, p1 = 0.f, p2 = 0.f, p3 = 0.f;
                ACC8(f00, 0)  ACC8(f01, 4)  ACC8(f10, 16) ACC8(f11, 20)
                const float part = (p0 + p1) + (p2 + p3);

                ab[n] = part;               // broadcast (same-wave, in-order DS)
                #pragma unroll
                for (int kk = 0; kk < 8; ++kk) {
                    const float4 t4 = *(const float4*)&ab[kk * 4];
                    Ar[4 * kk] = t4.x; Ar[4 * kk + 1] = t4.y;
                    Ar[4 * kk + 2] = t4.z; Ar[4 * kk + 3] = t4.w;
                }
                if (k == 3) {               // local norm: no cross-lane
                    float mm = Ar[0];
                    #pragma unroll
                    for (int r = 1; r < 32; ++r) mm = fmaxf(mm, Ar[r]);
                    const float rn = __builtin_amdgcn_rcpf(mm);
                    #pragma unroll
                    for (int r = 0; r < 32; ++r) Ar[r] *= rn;
                    Lacc += __logf(mm);
                }
            }
        }
        #undef ACC8

        ab[n] = Ar[n];                      // publish final u / v
        if (lane == 0) lb[wib] = Lacc;
    }

    __syncthreads();                        // u, v, Laccs visible

    if (wib != 0) return;

    // ---- finalize (wave0): dot(u,v) fully local, then plain store ----
    float dot = 0.f;
    #pragma unroll
    for (int k = 0; k < 8; ++k) {
        const float4 tu = *(const float4*)&abuf[0][k * 4];
        const float4 tv = *(const float4*)&abuf[1][k * 4];
        dot = fmaf(tu.x, tv.x, dot);
        dot = fmaf(tu.y, tv.y, dot);
        dot = fmaf(tu.z, tv.z, dot);
        dot = fmaf(tu.w, tv.w, dot);
    }

    float scor = (lane < 8) ? wspart[(size_t)b * 32 + lane * 4]     : 0.0f;
    float msum = (lane < 8) ? wspart[(size_t)b * 32 + lane * 4 + 1] : 0.0f;
    float ntot = (lane < 8) ? wspart[(size_t)b * 32 + lane * 4 + 2] : 0.0f;
    #pragma unroll
    for (int d = 16; d > 0; d >>= 1) {
        ntot += __shfl_xor(ntot, d, 32);
        msum += __shfl_xor(msum, d, 32);
        scor += __shfl_xor(scor, d, 32);
    }
    if (lane == 0) {
        const int len = (int)(msum + 0.5f);
        const int lt  = tags[b * S_N + len - 1];
        const float res = lb[0] + lb[1] + __logf(dot) + ntot * SCALE_LOG
                          - endT[lt] - scor;
        wspart[WS_RES_OFF + b] = res;       // plain store: zero contention
    }
}

// 1 wave: sum the 512 per-block results, write out
__global__ __launch_bounds__(64) void crf_reduce(
    const float* __restrict__ wspart, float* __restrict__ out)
{
    const int lane = threadIdx.x;
    float x = 0.f;
    #pragma unroll
    for (int i = 0; i < 8; ++i) x += wspart[WS_RES_OFF + lane + i * 64];
    #pragma unroll
    for (int d = 32; d > 0; d >>= 1) x += __shfl_xor(x, d, 64);
    if (lane == 0) out[0] = x;
}

extern "C" void kernel_launch(void* const* d_in, const int* in_sizes, int n_in,
                              void* d_out, int out_size, void* d_ws, size_t ws_size,
                              hipStream_t stream) {
    const float* em     = (const float*)d_in[0];
    const int*   tags   = (const int*)  d_in[1];
    const float* mask   = (const float*)d_in[2];
    const float* trans  = (const float*)d_in[3];
    const float* startT = (const float*)d_in[4];
    const float* endT   = (const float*)d_in[5];

    // one block per batch: 8 waves x 4 chunks; waves 4-7 transposed products;
    // 64 KiB LDS -> 2 blocks/CU, 16 waves/CU
    hipLaunchKernelGGL(crf_fused, dim3(B_N), dim3(512), 0, stream,
                       em, tags, mask, trans, startT, endT,
                       (float*)d_ws, (float*)d_out);
    // tiny follow-up: contention-free sum of the 512 block results
    hipLaunchKernelGGL(crf_reduce, dim3(1), dim3(64), 0, stream,
                       (const float*)d_ws, (float*)d_out);
}

// Round 12
// 136.508 us; speedup vs baseline: 1.0484x; 1.0484x over previous
//
#include <hip/hip_runtime.h>
#include <hip/hip_fp16.h>

// CRF NLL on MI355X — round 21: bidirectional combine, TRANSPOSED-STORE flavor.
//
// r20 post-mortem: the idea (halve the serial combine tail via a beta chain
// over chunks 16-31) was right, but implementing it with a second transposed
// chunk-chain (tchain4/tchain1 + divergent A/D-init) spilled 64B/thread
// (WRITE 86KB -> 17MB) and regressed. r21 keeps ALL chain code identical for
// all 8 waves (no spill vector) and moves the transpose to the fragment
// STORE of waves 4-7: element (r,n) -> row-major LDS, XOR-swizzled
// (chunk' = (n>>3) ^ ((r>>1)&3)) so beta's per-iter 4x ds_read_b128 are
// ~4-way conflicted (1.6x, m136) instead of 16-way. Store side: 16 one-time
// ds_write_b16/lane/chunk. Combine: wave0 alpha over 0..15 (code unchanged)
// CONCURRENT with wave1 beta v<-F_c*v over 31..16 (replicated v, rows);
// barrier; wave0 finishes log(u.v). Serial tail 32 -> 16 iterations.
// Epilogue: plain store + 1-wave reduce kernel (r18, best).
//
// ws layout (dwords): [0,16384) per-wave score/msum/napp slots (b*32+w*4);
//   [16384, 16896) per-block results.
// Scale 2^-6.5 per applied matrix (exact: added back as napp*6.5*ln2).

typedef __attribute__((ext_vector_type(8)))  _Float16 half8;
typedef __attribute__((ext_vector_type(2)))  _Float16 half2v;
typedef __attribute__((ext_vector_type(16))) float    f32x16;
typedef __attribute__((ext_vector_type(4)))  unsigned uint4v;

#define S_N 1024
#define T_N 32
#define B_N 512
#define L_CH 32
#define C_CH 32
#define SCALE_MUL 0.011048543456039806f   // 2^-6.5 folded into ee
#define SCALE_LOG 4.505456673639645f      // 6.5*ln2 per applied matrix

#define WS_RES_OFF 16384                  // dword offset of per-block results

__device__ __forceinline__ unsigned pkrtz(float lo, float hi) {
    return __builtin_bit_cast(unsigned, __builtin_amdgcn_cvt_pkrtz(lo, hi));
}
__device__ __forceinline__ unsigned pmul(unsigned a, unsigned b) {
    const __half2 r = __builtin_bit_cast(__half2, a) * __builtin_bit_cast(__half2, b);
    return __builtin_bit_cast(unsigned, r);
}
__device__ __forceinline__ half8 mkh8(const unsigned* a) {
    uint4v u = {a[0], a[1], a[2], a[3]};
    return __builtin_bit_cast(half8, u);
}
__device__ __forceinline__ float hlo(unsigned u) {
    return (float)__builtin_bit_cast(half2v, u).x;
}
__device__ __forceinline__ float hhi(unsigned u) {
    return (float)__builtin_bit_cast(half2v, u).y;
}
// PI: involution swapping rows 4-7<->8-11 and 20-23<->24-27
__device__ __forceinline__ int PIx(int x) { return (x & ~12) | ((x & 4) << 1) | ((x & 8) >> 1); }

__device__ __forceinline__ f32x16 packmm(const f32x16& D, uint4 su, uint4 sv,
                                         half8 A1v, half8 A2v) {
    unsigned S[8];
    S[0] = pmul(pkrtz(D[0],  D[1]),  su.x);
    S[1] = pmul(pkrtz(D[2],  D[3]),  su.y);
    S[2] = pmul(pkrtz(D[4],  D[5]),  su.z);
    S[3] = pmul(pkrtz(D[6],  D[7]),  su.w);
    S[4] = pmul(pkrtz(D[8],  D[9]),  sv.x);
    S[5] = pmul(pkrtz(D[10], D[11]), sv.y);
    S[6] = pmul(pkrtz(D[12], D[13]), sv.z);
    S[7] = pmul(pkrtz(D[14], D[15]), sv.w);
    const f32x16 Z = {};
    f32x16 t = __builtin_amdgcn_mfma_f32_32x32x16_f16(A1v, mkh8(&S[0]), Z, 0, 0, 0);
    return   __builtin_amdgcn_mfma_f32_32x32x16_f16(A2v, mkh8(&S[4]), t, 0, 0, 0);
}
__device__ __forceinline__ void step1(f32x16& D, const unsigned* mq, int r, int h,
                                      half8 A1v, half8 A2v) {
    const uint4 su = *(const uint4*)(mq + r * 16 + h * 8);
    const uint4 sv = *(const uint4*)(mq + r * 16 + h * 8 + 4);
    D = packmm(D, su, sv, A1v, A2v);
}

template<bool CLEAN>
__device__ __forceinline__ void chain4(
    const unsigned* m0, const unsigned* m1,
    const unsigned* m2, const unsigned* m3,
    f32x16& D0, f32x16& D1, f32x16& D2, f32x16& D3,
    unsigned mb0, unsigned mb1, unsigned mb2, unsigned mb3,
    int h, half8 A1v, half8 A2v) {
    if (CLEAN) {
        #pragma unroll 2
        for (int r = L_CH - 1; r >= 1; --r) {
            const uint4 su0 = *(const uint4*)(m0 + r * 16 + h * 8);
            const uint4 sv0 = *(const uint4*)(m0 + r * 16 + h * 8 + 4);
            const uint4 su1 = *(const uint4*)(m1 + r * 16 + h * 8);
            const uint4 sv1 = *(const uint4*)(m1 + r * 16 + h * 8 + 4);
            const uint4 su2 = *(const uint4*)(m2 + r * 16 + h * 8);
            const uint4 sv2 = *(const uint4*)(m2 + r * 16 + h * 8 + 4);
            const uint4 su3 = *(const uint4*)(m3 + r * 16 + h * 8);
            const uint4 sv3 = *(const uint4*)(m3 + r * 16 + h * 8 + 4);
            D0 = packmm(D0, su0, sv0, A1v, A2v);
            D1 = packmm(D1, su1, sv1, A1v, A2v);
            D2 = packmm(D2, su2, sv2, A1v, A2v);
            D3 = packmm(D3, su3, sv3, A1v, A2v);
        }
        if (mb0 & 1u) step1(D0, m0, 0, h, A1v, A2v);   // chunk 0 has bit0 cleared
        if (mb1 & 1u) step1(D1, m1, 0, h, A1v, A2v);
        if (mb2 & 1u) step1(D2, m2, 0, h, A1v, A2v);
        if (mb3 & 1u) step1(D3, m3, 0, h, A1v, A2v);
    } else {
        for (int r = L_CH - 1; r >= 0; --r) {
            if ((mb0 >> r) & 1u) step1(D0, m0, r, h, A1v, A2v);
            if ((mb1 >> r) & 1u) step1(D1, m1, r, h, A1v, A2v);
            if ((mb2 >> r) & 1u) step1(D2, m2, r, h, A1v, A2v);
            if ((mb3 >> r) & 1u) step1(D3, m3, r, h, A1v, A2v);
        }
    }
}

__global__ __attribute__((amdgpu_flat_work_group_size(512, 512),
                          amdgpu_waves_per_eu(4, 4)))
void crf_fused(
    const float* __restrict__ em, const int* __restrict__ tags,
    const float* __restrict__ mask, const float* __restrict__ trans,
    const float* __restrict__ startT, const float* __restrict__ endT,
    float* __restrict__ wspart, float* __restrict__ out)
{
    __shared__ unsigned elds[C_CH][512];   // 64 KiB: scales, reused for fragments
    __shared__ float abuf[2][32];          // per-wave alpha/beta broadcast
    __shared__ float lb[2];                // Lacc_alpha, Lacc_beta

    const int wib  = threadIdx.x >> 6;     // 0..7
    const int lane = threadIdx.x & 63;
    const int n    = lane & 31;
    const int h    = lane >> 5;
    const int b    = blockIdx.x;
    const int c0   = wib * 4;              // this wave's first chunk
    const bool betaw = (wib >= 4);         // chunks 16-31: transposed STORE only

    // ---- issue pair-0 emission loads immediately (16B/lane, linear) ----
    float4 P0[4], P1[4];
    {
        const float4* eq0 = (const float4*)(em + ((size_t)b * S_N + (c0 + 0) * L_CH) * T_N);
        const float4* eq1 = (const float4*)(em + ((size_t)b * S_N + (c0 + 1) * L_CH) * T_N);
        #pragma unroll
        for (int i = 0; i < 4; ++i) P0[i] = eq0[i * 64 + lane];
        #pragma unroll
        for (int i = 0; i < 4; ++i) P1[i] = eq1[i * 64 + lane];
    }

    // ---- mask ballots (4 chunks = 128 positions) + path-score partial ----
    unsigned mb_[4];
    {
        float vacc = 0.f, macc = 0.f;
        #pragma unroll
        for (int q2 = 0; q2 < 2; ++q2) {
            const int s  = c0 * L_CH + q2 * 64 + lane;
            const float mv = mask[b * S_N + s];
            const unsigned long long mb = __ballot(mv != 0.0f);
            mb_[2 * q2]     = (unsigned)mb;
            mb_[2 * q2 + 1] = (unsigned)(mb >> 32);
            const int tc = tags[b * S_N + s];
            int tp = __shfl_up(tc, 1, 64);
            float val;
            if (lane == 0) {
                if (s == 0) {
                    val = startT[tc] + em[(size_t)b * S_N * T_N + tc];
                } else {
                    tp = tags[b * S_N + s - 1];
                    val = mv * (em[((size_t)b * S_N + s) * T_N + tc] + trans[tp * 32 + tc]);
                }
            } else {
                val = mv * (em[((size_t)b * S_N + s) * T_N + tc] + trans[tp * 32 + tc]);
            }
            vacc += val; macc += mv;
        }
        if (c0 == 0) mb_[0] &= ~1u;        // t=0 has no transition matrix
        #pragma unroll
        for (int d = 32; d > 0; d >>= 1) {
            vacc += __shfl_xor(vacc, d, 64);
            macc += __shfl_xor(macc, d, 64);
        }
        if (lane == 0) {
            float* slot = wspart + (size_t)b * 32 + wib * 4;
            slot[0] = vacc;
            slot[1] = macc;
            slot[2] = (float)(__popc(mb_[0]) + __popc(mb_[1]) +
                              __popc(mb_[2]) + __popc(mb_[3]));
        }
    }

    // pack loaded f32 quads -> f16 scale pairs in D-reg-pair LDS order.
    #define PACKQ(P, qc) { \
        unsigned* mq = elds[qc]; \
        _Pragma("unroll") \
        for (int i = 0; i < 4; ++i) { \
            const int f = i * 64 + lane; \
            const int r_ = f >> 3; \
            const int m_ = ((f & 1) << 3) | (f & 6); \
            const unsigned pk0 = pkrtz(__expf(P[i].x) * SCALE_MUL, __expf(P[i].y) * SCALE_MUL); \
            const unsigned pk1 = pkrtz(__expf(P[i].z) * SCALE_MUL, __expf(P[i].w) * SCALE_MUL); \
            *(uint2*)(mq + r_ * 16 + m_) = make_uint2(pk0, pk1); \
        } }

    PACKQ(P0, c0)
    PACKQ(P1, c0 + 1)

    // ---- issue pair-1 loads; latency covered by A-frag setup + D-init ----
    {
        const float4* eq2 = (const float4*)(em + ((size_t)b * S_N + (c0 + 2) * L_CH) * T_N);
        const float4* eq3 = (const float4*)(em + ((size_t)b * S_N + (c0 + 3) * L_CH) * T_N);
        #pragma unroll
        for (int i = 0; i < 4; ++i) P0[i] = eq2[i * 64 + lane];
        #pragma unroll
        for (int i = 0; i < 4; ++i) P1[i] = eq3[i * 64 + lane];
    }

    // ---- loop-invariant A fragments: f16(exp(trans)), PI-permuted cols ----
    unsigned A1[4], A2[4];
    #pragma unroll
    for (int j = 0; j < 4; ++j) {
        const int k1 = PIx(8 * h + 2 * j);
        const int k2 = PIx(16 + 8 * h + 2 * j);
        A1[j] = pkrtz(__expf(trans[n * 32 + k1]), __expf(trans[n * 32 + k1 + 1]));
        A2[j] = pkrtz(__expf(trans[n * 32 + k2]), __expf(trans[n * 32 + k2 + 1]));
    }
    const half8 A1v = mkh8(A1), A2v = mkh8(A2);

    // ---- 4 chain states: identity in C layout ----
    f32x16 D0, D1, D2, D3;
    #pragma unroll
    for (int i = 0; i < 16; ++i) {
        const int row = (i & 3) + 8 * (i >> 2) + 4 * h;
        const float v = (row == n) ? 1.0f : 0.0f;
        D0[i] = v; D1[i] = v; D2[i] = v; D3[i] = v;
    }

    PACKQ(P0, c0 + 2)
    PACKQ(P1, c0 + 3)
    #undef PACKQ

    const bool allclean =
        ((mb_[0] | (c0 == 0 ? 1u : 0u)) == 0xFFFFFFFFu) &&
        (mb_[1] == 0xFFFFFFFFu) && (mb_[2] == 0xFFFFFFFFu) && (mb_[3] == 0xFFFFFFFFu);

    if (allclean)
        chain4<true >(elds[c0], elds[c0 + 1], elds[c0 + 2], elds[c0 + 3],
                      D0, D1, D2, D3, mb_[0], mb_[1], mb_[2], mb_[3], h, A1v, A2v);
    else
        chain4<false>(elds[c0], elds[c0 + 1], elds[c0 + 2], elds[c0 + 3],
                      D0, D1, D2, D3, mb_[0], mb_[1], mb_[2], mb_[3], h, A1v, A2v);

    // ---- fragment store ----
    // alpha waves (0-3): dense SoA column-major (as before), conflict-free.
    // beta waves (4-7): row-major TRANSPOSED, XOR-swizzled 16B chunks so the
    // beta combine's ds_read_b128 rows are ~4-way instead of 16-way.
    // element (row r, col n) -> half index r*32 + ((n>>3)^((r>>1)&3))*8 + (n&7)
    if (!betaw) {
        #define STOREF(D, qc) { \
            unsigned* dst = elds[qc]; \
            ((uint4*)dst)[lane]      = make_uint4(pkrtz(D[0], D[1]),   pkrtz(D[2], D[3]), \
                                                  pkrtz(D[4], D[5]),   pkrtz(D[6], D[7])); \
            ((uint4*)dst)[64 + lane] = make_uint4(pkrtz(D[8], D[9]),   pkrtz(D[10], D[11]), \
                                                  pkrtz(D[12], D[13]), pkrtz(D[14], D[15])); \
        }
        STOREF(D0, c0) STOREF(D1, c0 + 1) STOREF(D2, c0 + 2) STOREF(D3, c0 + 3)
        #undef STOREF
    } else {
        #define STOREFT(D, qc) { \
            __half* dst = (__half*)elds[qc]; \
            _Pragma("unroll") \
            for (int i = 0; i < 16; ++i) { \
                const int r_ = (i & 3) + 8 * ((i >> 2) & 1) + 16 * (i >> 3) + 4 * h; \
                const int cx = (n >> 3) ^ ((r_ >> 1) & 3); \
                dst[r_ * 32 + cx * 8 + (n & 7)] = (__half)D[i]; \
            } }
        STOREFT(D0, c0) STOREFT(D1, c0 + 1) STOREFT(D2, c0 + 2) STOREFT(D3, c0 + 3)
        #undef STOREFT
    }

    __syncthreads();                        // all fragments + ws slots visible

    // ---- bidirectional combine: wave0 alpha (0..15), wave1 beta (31..16) ----
    if (wib == 0) {
        float* ab = abuf[0];
        float Ar[32];
        const float a0 = startT[n] + em[(size_t)b * S_N * T_N + n];
        ab[n] = a0;
        #pragma unroll
        for (int k = 0; k < 8; ++k) {
            const float4 t = *(const float4*)&ab[k * 4];
            Ar[4 * k] = t.x; Ar[4 * k + 1] = t.y; Ar[4 * k + 2] = t.z; Ar[4 * k + 3] = t.w;
        }
        float mx = Ar[0];
        #pragma unroll
        for (int r = 1; r < 32; ++r) mx = fmaxf(mx, Ar[r]);
        float Lacc = mx;
        #pragma unroll
        for (int r = 0; r < 32; ++r) Ar[r] = __expf(Ar[r] - mx);

        #define ACC8(f, B) { \
            p0 = fmaf(Ar[(B) + 0],  hlo((f).x), p0); \
            p1 = fmaf(Ar[(B) + 1],  hhi((f).x), p1); \
            p2 = fmaf(Ar[(B) + 2],  hlo((f).y), p2); \
            p3 = fmaf(Ar[(B) + 3],  hhi((f).y), p3); \
            p0 = fmaf(Ar[(B) + 8],  hlo((f).z), p0); \
            p1 = fmaf(Ar[(B) + 9],  hhi((f).z), p1); \
            p2 = fmaf(Ar[(B) + 10], hlo((f).w), p2); \
            p3 = fmaf(Ar[(B) + 11], hhi((f).w), p3); }
        for (int cc = 0; cc < 4; ++cc) {
            #pragma unroll
            for (int k = 0; k < 4; ++k) {
                const unsigned* ch = elds[cc * 4 + k];
                const uint4 f00 = *(const uint4*)(ch + n * 4);
                const uint4 f01 = *(const uint4*)(ch + (n + 32) * 4);
                const uint4 f10 = *(const uint4*)(ch + 256 + n * 4);
                const uint4 f11 = *(const uint4*)(ch + 256 + (n + 32) * 4);
                float p0 = 0.f, p1 = 0.f, p2 = 0.f, p3 = 0.f;
                ACC8(f00, 0)  ACC8(f01, 4)  ACC8(f10, 16) ACC8(f11, 20)
                const float part = (p0 + p1) + (p2 + p3);
                ab[n] = part;
                #pragma unroll
                for (int kk = 0; kk < 8; ++kk) {
                    const float4 t4 = *(const float4*)&ab[kk * 4];
                    Ar[4 * kk] = t4.x; Ar[4 * kk + 1] = t4.y;
                    Ar[4 * kk + 2] = t4.z; Ar[4 * kk + 3] = t4.w;
                }
                if (k == 3) {
                    float mm = Ar[0];
                    #pragma unroll
                    for (int r = 1; r < 32; ++r) mm = fmaxf(mm, Ar[r]);
                    const float rn = __builtin_amdgcn_rcpf(mm);
                    #pragma unroll
                    for (int r = 0; r < 32; ++r) Ar[r] *= rn;
                    Lacc += __logf(mm);
                }
            }
        }
        #undef ACC8
        ab[n] = Ar[n];                      // publish u
        if (lane == 0) lb[0] = Lacc;
    } else if (wib == 1) {
        float* ab = abuf[1];
        float Ar[32];
        float Lacc = 0.0f;
        #pragma unroll
        for (int k = 0; k < 8; ++k) {
            const float4 t = *(const float4*)&endT[k * 4];
            Ar[4 * k]     = __expf(t.x);
            Ar[4 * k + 1] = __expf(t.y);
            Ar[4 * k + 2] = __expf(t.z);
            Ar[4 * k + 3] = __expf(t.w);
        }
        const int sw = (n >> 1) & 3;
        // v_new[n] = sum_k F[n][k]*v[k]; row n read from swizzled row-major.
        #define ACC8T(f, B) { \
            p0 = fmaf(Ar[(B) + 0], hlo((f).x), p0); \
            p1 = fmaf(Ar[(B) + 1], hhi((f).x), p1); \
            p2 = fmaf(Ar[(B) + 2], hlo((f).y), p2); \
            p3 = fmaf(Ar[(B) + 3], hhi((f).y), p3); \
            p0 = fmaf(Ar[(B) + 4], hlo((f).z), p0); \
            p1 = fmaf(Ar[(B) + 5], hhi((f).z), p1); \
            p2 = fmaf(Ar[(B) + 6], hlo((f).w), p2); \
            p3 = fmaf(Ar[(B) + 7], hhi((f).w), p3); }
        for (int cc = 0; cc < 4; ++cc) {
            #pragma unroll
            for (int k = 0; k < 4; ++k) {
                const int c = 31 - (cc * 4 + k);
                const unsigned* ch = elds[c];
                const uint4 g0 = *(const uint4*)(ch + n * 16 + (0 ^ sw) * 4);
                const uint4 g1 = *(const uint4*)(ch + n * 16 + (1 ^ sw) * 4);
                const uint4 g2 = *(const uint4*)(ch + n * 16 + (2 ^ sw) * 4);
                const uint4 g3 = *(const uint4*)(ch + n * 16 + (3 ^ sw) * 4);
                float p0 = 0.f, p1 = 0.f, p2 = 0.f, p3 = 0.f;
                ACC8T(g0, 0)  ACC8T(g1, 8)  ACC8T(g2, 16) ACC8T(g3, 24)
                const float part = (p0 + p1) + (p2 + p3);
                ab[n] = part;
                #pragma unroll
                for (int kk = 0; kk < 8; ++kk) {
                    const float4 t4 = *(const float4*)&ab[kk * 4];
                    Ar[4 * kk] = t4.x; Ar[4 * kk + 1] = t4.y;
                    Ar[4 * kk + 2] = t4.z; Ar[4 * kk + 3] = t4.w;
                }
                if (k == 3) {
                    float mm = Ar[0];
                    #pragma unroll
                    for (int r = 1; r < 32; ++r) mm = fmaxf(mm, Ar[r]);
                    const float rn = __builtin_amdgcn_rcpf(mm);
                    #pragma unroll
                    for (int r = 0; r < 32; ++r) Ar[r] *= rn;
                    Lacc += __logf(mm);
                }
            }
        }
        #undef ACC8T
        ab[n] = Ar[n];                      // publish v
        if (lane == 0) lb[1] = Lacc;
    }

    __syncthreads();                        // u, v, Laccs visible

    if (wib != 0) return;

    // ---- finalize (wave0): dot(u,v) fully local, then plain store ----
    float dot = 0.f;
    #pragma unroll
    for (int k = 0; k < 8; ++k) {
        const float4 tu = *(const float4*)&abuf[0][k * 4];
        const float4 tv = *(const float4*)&abuf[1][k * 4];
        dot = fmaf(tu.x, tv.x, dot);
        dot = fmaf(tu.y, tv.y, dot);
        dot = fmaf(tu.z, tv.z, dot);
        dot = fmaf(tu.w, tv.w, dot);
    }

    float scor = (lane < 8) ? wspart[(size_t)b * 32 + lane * 4]     : 0.0f;
    float msum = (lane < 8) ? wspart[(size_t)b * 32 + lane * 4 + 1] : 0.0f;
    float ntot = (lane < 8) ? wspart[(size_t)b * 32 + lane * 4 + 2] : 0.0f;
    #pragma unroll
    for (int d = 16; d > 0; d >>= 1) {
        ntot += __shfl_xor(ntot, d, 32);
        msum += __shfl_xor(msum, d, 32);
        scor += __shfl_xor(scor, d, 32);
    }
    if (lane == 0) {
        const int len = (int)(msum + 0.5f);
        const int lt  = tags[b * S_N + len - 1];
        const float res = lb[0] + lb[1] + __logf(dot) + ntot * SCALE_LOG
                          - endT[lt] - scor;
        wspart[WS_RES_OFF + b] = res;       // plain store: zero contention
    }
}

// 1 wave: sum the 512 per-block results, write out
__global__ __launch_bounds__(64) void crf_reduce(
    const float* __restrict__ wspart, float* __restrict__ out)
{
    const int lane = threadIdx.x;
    float x = 0.f;
    #pragma unroll
    for (int i = 0; i < 8; ++i) x += wspart[WS_RES_OFF + lane + i * 64];
    #pragma unroll
    for (int d = 32; d > 0; d >>= 1) x += __shfl_xor(x, d, 64);
    if (lane == 0) out[0] = x;
}

extern "C" void kernel_launch(void* const* d_in, const int* in_sizes, int n_in,
                              void* d_out, int out_size, void* d_ws, size_t ws_size,
                              hipStream_t stream) {
    const float* em     = (const float*)d_in[0];
    const int*   tags   = (const int*)  d_in[1];
    const float* mask   = (const float*)d_in[2];
    const float* trans  = (const float*)d_in[3];
    const float* startT = (const float*)d_in[4];
    const float* endT   = (const float*)d_in[5];

    // one block per batch: 8 waves x 4 chunks; waves 4-7 store transposed;
    // 64 KiB LDS -> 2 blocks/CU, 16 waves/CU
    hipLaunchKernelGGL(crf_fused, dim3(B_N), dim3(512), 0, stream,
                       em, tags, mask, trans, startT, endT,
                       (float*)d_ws, (float*)d_out);
    // tiny follow-up: contention-free sum of the 512 block results
    hipLaunchKernelGGL(crf_reduce, dim3(1), dim3(64), 0, stream,
                       (const float*)d_ws, (float*)d_out);
}